// Round 6
// baseline (954.614 us; speedup 1.0000x reference)
//
#include <hip/hip_runtime.h>
#include <math.h>

#define Bn 16
#define Tn 16384
#define Fn 32
#define Cn 64
#define Ln 10
#define ST 76   // LDS tile row stride (elements): 152B -> conflict-free patterns

typedef _Float16 v8h  __attribute__((ext_vector_type(8)));
typedef _Float16 v4h  __attribute__((ext_vector_type(4)));
typedef float    v16f __attribute__((ext_vector_type(16)));
typedef float    v4f  __attribute__((ext_vector_type(4)));

// ---------------------------------------------------------------------------
// k_prep: pack weights fp32 -> fp16 in MFMA A-operand layouts.
// wfg16[l][row<128][k'<192]: row<64 -> fw[l][row][ci][tap] at k'=tap*64+ci,
//                            row>=64 -> gw (same layout)
// rs16 [l][row<128][ci<64] : row<64 -> rw, row>=64 -> sw
// ---------------------------------------------------------------------------
__global__ __launch_bounds__(256) void k_prep(const float* __restrict__ fw,
                                              const float* __restrict__ gw,
                                              const float* __restrict__ rw,
                                              const float* __restrict__ sw,
                                              _Float16* __restrict__ wfg16,
                                              _Float16* __restrict__ rs16)
{
    int gid = blockIdx.x * 256 + threadIdx.x;
    if (gid < Ln * 128 * 192) {
        int l   = gid / (128 * 192);
        int rem = gid % (128 * 192);
        int row = rem / 192, k = rem % 192;
        int tap = k >> 6, ci = k & 63, co = row & 63;
        const float* wsrc = (row < 64) ? fw : gw;
        wfg16[gid] = (_Float16)wsrc[((l * 64 + co) * 64 + ci) * 3 + tap];
    }
    int gid2 = gid - Ln * 128 * 192;
    if (gid2 >= 0 && gid2 < Ln * 128 * 64) {
        int l   = gid2 / (128 * 64);
        int rem = gid2 % (128 * 64);
        int row = rem / 64, ci = rem & 63, co = row & 63;
        const float* wsrc = (row < 64) ? rw : sw;
        rs16[gid2] = (_Float16)wsrc[(l * 64 + co) * 64 + ci];
    }
}

// ---------------------------------------------------------------------------
// k_input: h[b][t][c] = fp16( sum_f w_in[c][f] * x[b][t][f] + b_in[c] )
// ---------------------------------------------------------------------------
__global__ __launch_bounds__(256) void k_input(const float* __restrict__ x,
                                               const float* __restrict__ w_in,
                                               const float* __restrict__ b_in,
                                               _Float16* __restrict__ h)
{
    const int t  = blockIdx.x * 256 + threadIdx.x;
    const int bb = blockIdx.y;
    const float* xp = x + ((size_t)bb * Tn + t) * Fn;
    float xv[32];
    #pragma unroll
    for (int i = 0; i < 8; ++i) {
        v4f v = *(const v4f*)&xp[i * 4];
        xv[i*4+0] = v[0]; xv[i*4+1] = v[1]; xv[i*4+2] = v[2]; xv[i*4+3] = v[3];
    }
    _Float16* hp = h + ((size_t)bb * Tn + t) * 64;
    #pragma unroll
    for (int c8 = 0; c8 < 8; ++c8) {
        v8h o;
        #pragma unroll
        for (int j = 0; j < 8; ++j) {
            int c = c8 * 8 + j;
            float a = b_in[c];
            #pragma unroll
            for (int f = 0; f < 32; ++f) a = fmaf(w_in[c * 32 + f], xv[f], a);
            o[j] = (_Float16)a;
        }
        *(v8h*)&hp[c8 * 8] = o;
    }
}

// ---------------------------------------------------------------------------
// k_layer: one WaveNet layer. Weights direct from global (L1/L2-resident).
// Tap tiles register-prefetched then staged into double-buffered LDS; 4
// barriers total. Biases pre-loaded into MFMA accumulators. Epilogue writes
// hout/skip directly from D-layout regs (residual & skip prefetched in
// D-layout, latency hidden behind the act phase).
// Block 256 = 4 waves; tile 64co x 128t; wave tile 32co x 64t.
// mfma_f32_32x32x16_f16: A[m=lane&31][k=(lane>>5)*8+j], B[k][n=lane&31],
// D: col(n)=lane&31, row(m)=(reg&3)+8*(reg>>2)+4*(lane>>5).
// ---------------------------------------------------------------------------
__global__ __launch_bounds__(256, 3) void k_layer(
    const _Float16* __restrict__ hin, _Float16* __restrict__ hout,
    _Float16* __restrict__ skip,
    const _Float16* __restrict__ wfg,   // [128][192] f rows 0-63, g rows 64-127
    const _Float16* __restrict__ rs,    // [128][64]  r rows 0-63, s rows 64-127
    const float* __restrict__ fb, const float* __restrict__ gb,
    const float* __restrict__ rb, const float* __restrict__ sb,
    const int dil, const float skip_scale)
{
    __shared__ _Float16 P0[128 * ST];   // 19.5KB
    __shared__ _Float16 P1[128 * ST];   // 19.5KB

    const int tid  = threadIdx.x;
    const int lane = tid & 63;
    const int wv   = tid >> 6;
    const int ch   = (wv & 1) * 32;     // co-half
    const int tb   = (wv >> 1) * 64;    // t-half
    const int hl   = lane >> 5;
    const int ln31 = lane & 31;
    const int bb   = blockIdx.y;
    const int t0   = blockIdx.x * 128;
    const size_t hbase = (size_t)bb * Tn * 64;

    v8h zero8;
    #pragma unroll
    for (int j = 0; j < 8; ++j) zero8[j] = (_Float16)0.f;

    const int s_tl = tid >> 3;              // staging row base (0..31), step 32
    const int s_c  = (tid & 7) * 8;

#define LOADTAP(R, OFF) do {                                                  \
    _Pragma("unroll")                                                         \
    for (int it = 0; it < 4; ++it) {                                          \
        int tg = t0 + s_tl + it * 32 - (OFF);                                 \
        (R)[it] = (tg >= 0) ? *(const v8h*)&hin[hbase + (size_t)tg * 64 + s_c]\
                            : zero8;                                          \
    } } while (0)

#define WRITELDS(DST, R) do {                                                 \
    _Pragma("unroll")                                                         \
    for (int it = 0; it < 4; ++it)                                            \
        *(v8h*)&(DST)[(s_tl + it * 32) * ST + s_c] = (R)[it];                 \
    } while (0)

#define MFMA_TAP(SRC, TAP) do {                                               \
    _Pragma("unroll")                                                         \
    for (int kc = 0; kc < 4; ++kc) {                                          \
        const int kof = kc * 16 + hl * 8;                                     \
        v8h aF = *(const v8h*)&wfg[(ch + ln31) * 192 + (TAP) * 64 + kof];     \
        v8h aG = *(const v8h*)&wfg[(64 + ch + ln31) * 192 + (TAP) * 64 + kof];\
        v8h b0 = *(const v8h*)&(SRC)[(tb + ln31) * ST + kof];                 \
        v8h b1 = *(const v8h*)&(SRC)[(tb + 32 + ln31) * ST + kof];            \
        accF[0] = __builtin_amdgcn_mfma_f32_32x32x16_f16(aF, b0, accF[0], 0, 0, 0); \
        accF[1] = __builtin_amdgcn_mfma_f32_32x32x16_f16(aF, b1, accF[1], 0, 0, 0); \
        accG[0] = __builtin_amdgcn_mfma_f32_32x32x16_f16(aG, b0, accG[0], 0, 0, 0); \
        accG[1] = __builtin_amdgcn_mfma_f32_32x32x16_f16(aG, b1, accG[1], 0, 0, 0); \
    } } while (0)

    // biases -> accumulator init (D row m maps to c = ch + 8q + 4hl + r)
    v4f fb4[4], gb4[4], rb4[4], sb4[4];
    #pragma unroll
    for (int q = 0; q < 4; ++q) {
        fb4[q] = *(const v4f*)&fb[ch + 8 * q + 4 * hl];
        gb4[q] = *(const v4f*)&gb[ch + 8 * q + 4 * hl];
        rb4[q] = *(const v4f*)&rb[ch + 8 * q + 4 * hl];
        sb4[q] = *(const v4f*)&sb[ch + 8 * q + 4 * hl];
    }
    v16f accF[2], accG[2];
    #pragma unroll
    for (int q = 0; q < 4; ++q)
        #pragma unroll
        for (int r = 0; r < 4; ++r) {
            accF[0][q * 4 + r] = fb4[q][r]; accF[1][q * 4 + r] = fb4[q][r];
            accG[0][q * 4 + r] = gb4[q][r]; accG[1][q * 4 + r] = gb4[q][r];
        }

    v8h r0[4], r1[4], r2[4];
    LOADTAP(r0, 2 * dil);
    LOADTAP(r1, dil);
    WRITELDS(P0, r0);
    __syncthreads();                        // B1: drains r0+r1 together
    LOADTAP(r2, 0);
    MFMA_TAP(P0, 0);
    WRITELDS(P1, r1);
    __syncthreads();                        // B2: drains r2 (covered by tap0 mfma)
    MFMA_TAP(P1, 1);
    WRITELDS(P0, r2);
    __syncthreads();                        // B3
    MFMA_TAP(P0, 2);

    // D-layout prefetch of residual h and skip (consumed after B4; latency
    // hides behind act). 8B divergent loads; lines are L1/L2-hot.
    v4h hres[2][4], skpre[2][4];
    #pragma unroll
    for (int nt = 0; nt < 2; ++nt) {
        const int tg = t0 + tb + nt * 32 + ln31;
        #pragma unroll
        for (int q = 0; q < 4; ++q) {
            const size_t base = hbase + (size_t)tg * 64 + ch + 8 * q + 4 * hl;
            hres[nt][q]  = *(const v4h*)&hin[base];
            skpre[nt][q] = *(const v4h*)&skip[base];
        }
    }

    // act = tanh(f)*sigmoid(g) = (A-1)*rcp((A+1)*(1+B)), A=e^2f, B=e^-g
    #pragma unroll
    for (int nt = 0; nt < 2; ++nt) {
        const int tl = tb + nt * 32 + ln31;
        #pragma unroll
        for (int q = 0; q < 4; ++q) {
            v4h av;
            #pragma unroll
            for (int r = 0; r < 4; ++r) {
                float f = accF[nt][q * 4 + r];
                float g = accG[nt][q * 4 + r];
                float A = __expf(2.f * f);
                float B = __expf(-g);
                float tA = A + 1.f;
                float den = fmaf(tA, B, tA);
                av[r] = (_Float16)((A - 1.f) * __builtin_amdgcn_rcpf(den));
            }
            *(v4h*)&P1[tl * ST + ch + 8 * q + 4 * hl] = av;
        }
    }
    __syncthreads();                        // B4: act tile complete (drains prefetch)

    v16f accR[2], accS[2];
    #pragma unroll
    for (int q = 0; q < 4; ++q)
        #pragma unroll
        for (int r = 0; r < 4; ++r) {
            accR[0][q * 4 + r] = rb4[q][r]; accR[1][q * 4 + r] = rb4[q][r];
            accS[0][q * 4 + r] = sb4[q][r]; accS[1][q * 4 + r] = sb4[q][r];
        }

    #pragma unroll
    for (int kc = 0; kc < 4; ++kc) {
        const int kof = kc * 16 + hl * 8;
        v8h aR = *(const v8h*)&rs[(ch + ln31) * 64 + kof];
        v8h aS = *(const v8h*)&rs[(64 + ch + ln31) * 64 + kof];
        v8h b0 = *(const v8h*)&P1[(tb + ln31) * ST + kof];
        v8h b1 = *(const v8h*)&P1[(tb + 32 + ln31) * ST + kof];
        accR[0] = __builtin_amdgcn_mfma_f32_32x32x16_f16(aR, b0, accR[0], 0, 0, 0);
        accR[1] = __builtin_amdgcn_mfma_f32_32x32x16_f16(aR, b1, accR[1], 0, 0, 0);
        accS[0] = __builtin_amdgcn_mfma_f32_32x32x16_f16(aS, b0, accS[0], 0, 0, 0);
        accS[1] = __builtin_amdgcn_mfma_f32_32x32x16_f16(aS, b1, accS[1], 0, 0, 0);
    }

    // epilogue: direct D-layout stores (L2 merges 8B chunks; no more barriers)
    #pragma unroll
    for (int nt = 0; nt < 2; ++nt) {
        const int tg = t0 + tb + nt * 32 + ln31;
        #pragma unroll
        for (int q = 0; q < 4; ++q) {
            const size_t base = hbase + (size_t)tg * 64 + ch + 8 * q + 4 * hl;
            v4h hn, sn;
            #pragma unroll
            for (int r = 0; r < 4; ++r) {
                hn[r] = (_Float16)(((float)hres[nt][q][r] + accR[nt][q * 4 + r]) * 0.7071f);
                sn[r] = (_Float16)((float)skpre[nt][q][r] * skip_scale + accS[nt][q * 4 + r]);
            }
            *(v4h*)&hout[base] = hn;
            *(v4h*)&skip[base] = sn;
        }
    }
#undef LOADTAP
#undef WRITELDS
#undef MFMA_TAP
}

// ---------------------------------------------------------------------------
// k_out: out[b][t] = ow2 @ relu(ow1 @ relu(skip[b][t][:]) + ob1) + ob2
// ---------------------------------------------------------------------------
__global__ __launch_bounds__(256) void k_out(const _Float16* __restrict__ skip,
                                             const float* __restrict__ ow1,
                                             const float* __restrict__ ob1,
                                             const float* __restrict__ ow2,
                                             const float* __restrict__ ob2,
                                             float* __restrict__ out)
{
    const int t  = blockIdx.x * 256 + threadIdx.x;
    const int bb = blockIdx.y;
    const _Float16* sp = skip + ((size_t)bb * Tn + t) * 64;
    float y[64];
    #pragma unroll
    for (int i = 0; i < 8; ++i) {
        v8h v = *(const v8h*)&sp[i * 8];
        #pragma unroll
        for (int j = 0; j < 8; ++j) y[i * 8 + j] = fmaxf((float)v[j], 0.f);
    }
    float o = ob2[0];
    for (int co = 0; co < 64; ++co) {          // weights uniform -> s_loads
        float a0 = ob1[co], a1 = 0.f;
        #pragma unroll
        for (int ci = 0; ci < 64; ci += 2) {
            a0 = fmaf(ow1[co * 64 + ci],     y[ci],     a0);
            a1 = fmaf(ow1[co * 64 + ci + 1], y[ci + 1], a1);
        }
        o = fmaf(ow2[co], fmaxf(a0 + a1, 0.f), o);
    }
    out[(size_t)bb * Tn + t] = o;
}

// ---------------------------------------------------------------------------
extern "C" void kernel_launch(void* const* d_in, const int* in_sizes, int n_in,
                              void* d_out, int out_size, void* d_ws, size_t ws_size,
                              hipStream_t stream)
{
    const float* x    = (const float*)d_in[0];
    const float* w_in = (const float*)d_in[1];
    const float* b_in = (const float*)d_in[2];
    const float* fw   = (const float*)d_in[3];
    const float* fb   = (const float*)d_in[4];
    const float* gw   = (const float*)d_in[5];
    const float* gb   = (const float*)d_in[6];
    const float* rw   = (const float*)d_in[7];
    const float* rb   = (const float*)d_in[8];
    const float* sw   = (const float*)d_in[9];
    const float* sb   = (const float*)d_in[10];
    const float* ow1  = (const float*)d_in[11];
    const float* ob1  = (const float*)d_in[12];
    const float* ow2  = (const float*)d_in[13];
    const float* ob2  = (const float*)d_in[14];
    float* out = (float*)d_out;

    const size_t n = (size_t)Bn * Tn * 64;
    _Float16* hA    = (_Float16*)d_ws;
    _Float16* hB    = hA + n;
    _Float16* skip  = hB + n;
    _Float16* wfg16 = skip + n;
    _Float16* rs16  = wfg16 + (size_t)Ln * 128 * 192;

    dim3 blk(256);
    k_prep<<<dim3((Ln * 128 * 192 + Ln * 128 * 64 + 255) / 256), blk, 0, stream>>>(
        fw, gw, rw, sw, wfg16, rs16);
    k_input<<<dim3(Tn / 256, Bn), blk, 0, stream>>>(x, w_in, b_in, hA);

    const _Float16* cur = hA;
    _Float16* nxt = hB;
    for (int l = 0; l < Ln; ++l) {
        const int d = 1 << l;                  // dilations 1..512
        k_layer<<<dim3(Tn / 128, Bn), blk, 0, stream>>>(
            cur, nxt, skip,
            wfg16 + (size_t)l * 128 * 192, rs16 + (size_t)l * 128 * 64,
            fb + l * Cn, gb + l * Cn, rb + l * Cn, sb + l * Cn,
            d, (l == 0) ? 0.f : 1.f);          // scale=0 absorbs 0xAA ws poison
        const _Float16* tmp = nxt; nxt = (_Float16*)cur; cur = tmp;
    }

    k_out<<<dim3(Tn / 256, Bn), blk, 0, stream>>>(skip, ow1, ob1, ow2, ob2, out);
}

// Round 7
// 679.734 us; speedup vs baseline: 1.4044x; 1.4044x over previous
//
#include <hip/hip_runtime.h>
#include <math.h>

#define Bn 16
#define Tn 16384
#define Fn 32
#define Cn 64
#define Ln 10
#define ST 76   // LDS tile row stride (elements): 152B -> conflict-free patterns

typedef _Float16 v8h  __attribute__((ext_vector_type(8)));
typedef _Float16 v4h  __attribute__((ext_vector_type(4)));
typedef float    v16f __attribute__((ext_vector_type(16)));
typedef float    v4f  __attribute__((ext_vector_type(4)));

// ---------------------------------------------------------------------------
// k_prep: pack weights fp32 -> fp16 in MFMA A-operand layouts.
// wfg16[l][row<128][k'<192]: row<64 -> fw[l][row][ci][tap] at k'=tap*64+ci,
//                            row>=64 -> gw (same layout)
// rs16 [l][row<128][ci<64] : row<64 -> rw, row>=64 -> sw
// ---------------------------------------------------------------------------
__global__ __launch_bounds__(256) void k_prep(const float* __restrict__ fw,
                                              const float* __restrict__ gw,
                                              const float* __restrict__ rw,
                                              const float* __restrict__ sw,
                                              _Float16* __restrict__ wfg16,
                                              _Float16* __restrict__ rs16)
{
    int gid = blockIdx.x * 256 + threadIdx.x;
    if (gid < Ln * 128 * 192) {
        int l   = gid / (128 * 192);
        int rem = gid % (128 * 192);
        int row = rem / 192, k = rem % 192;
        int tap = k >> 6, ci = k & 63, co = row & 63;
        const float* wsrc = (row < 64) ? fw : gw;
        wfg16[gid] = (_Float16)wsrc[((l * 64 + co) * 64 + ci) * 3 + tap];
    }
    int gid2 = gid - Ln * 128 * 192;
    if (gid2 >= 0 && gid2 < Ln * 128 * 64) {
        int l   = gid2 / (128 * 64);
        int rem = gid2 % (128 * 64);
        int row = rem / 64, ci = rem & 63, co = row & 63;
        const float* wsrc = (row < 64) ? rw : sw;
        rs16[gid2] = (_Float16)wsrc[(l * 64 + co) * 64 + ci];
    }
}

// ---------------------------------------------------------------------------
// k_input: h[b][t][c] = fp16( sum_f w_in[c][f] * x[b][t][f] + b_in[c] )
// ---------------------------------------------------------------------------
__global__ __launch_bounds__(256) void k_input(const float* __restrict__ x,
                                               const float* __restrict__ w_in,
                                               const float* __restrict__ b_in,
                                               _Float16* __restrict__ h)
{
    const int t  = blockIdx.x * 256 + threadIdx.x;
    const int bb = blockIdx.y;
    const float* xp = x + ((size_t)bb * Tn + t) * Fn;
    float xv[32];
    #pragma unroll
    for (int i = 0; i < 8; ++i) {
        v4f v = *(const v4f*)&xp[i * 4];
        xv[i*4+0] = v[0]; xv[i*4+1] = v[1]; xv[i*4+2] = v[2]; xv[i*4+3] = v[3];
    }
    _Float16* hp = h + ((size_t)bb * Tn + t) * 64;
    #pragma unroll
    for (int c8 = 0; c8 < 8; ++c8) {
        v8h o;
        #pragma unroll
        for (int j = 0; j < 8; ++j) {
            int c = c8 * 8 + j;
            float a = b_in[c];
            #pragma unroll
            for (int f = 0; f < 32; ++f) a = fmaf(w_in[c * 32 + f], xv[f], a);
            o[j] = (_Float16)a;
        }
        *(v8h*)&hp[c8 * 8] = o;
    }
}

// ---------------------------------------------------------------------------
// k_layer: one WaveNet layer. R5 coalesced structure (every global access
// 16B/lane; D->[t][c] transposes through LDS) + R6's compute savings:
// biases pre-loaded into MFMA accumulators, act via rcp (no fp32 divides).
// Block 256 = 4 waves; tile 64co x 128t; wave tile 32co x 64t.
// mfma_f32_32x32x16_f16: A[m=lane&31][k=(lane>>5)*8+j], B[k][n=lane&31],
// D: col(n)=lane&31, row(m)=(reg&3)+8*(reg>>2)+4*(lane>>5).
// ---------------------------------------------------------------------------
__global__ __launch_bounds__(256, 4) void k_layer(
    const _Float16* __restrict__ hin, _Float16* __restrict__ hout,
    _Float16* __restrict__ skip,
    const _Float16* __restrict__ wfg,   // [128][192] f rows 0-63, g rows 64-127
    const _Float16* __restrict__ rs,    // [128][64]  r rows 0-63, s rows 64-127
    const float* __restrict__ fb, const float* __restrict__ gb,
    const float* __restrict__ rb, const float* __restrict__ sb,
    const int dil, const float skip_scale)
{
    __shared__ _Float16 P0[128 * ST];   // 19.5KB
    __shared__ _Float16 P1[128 * ST];   // 19.5KB

    const int tid  = threadIdx.x;
    const int lane = tid & 63;
    const int wv   = tid >> 6;
    const int ch   = (wv & 1) * 32;     // co-half
    const int tb   = (wv >> 1) * 64;    // t-half
    const int hl   = lane >> 5;
    const int ln31 = lane & 31;
    const int bb   = blockIdx.y;
    const int t0   = blockIdx.x * 128;
    const size_t hbase = (size_t)bb * Tn * 64;

    v8h zero8;
    #pragma unroll
    for (int j = 0; j < 8; ++j) zero8[j] = (_Float16)0.f;

    // coalesced tap staging: thread covers 4 x (tl, 8c) cells
    const int s_tl = tid >> 3;              // base row (0..31), rows step 32
    const int s_c  = (tid & 7) * 8;

#define STAGE(DST, OFF) do {                                                  \
    _Pragma("unroll")                                                         \
    for (int it = 0; it < 4; ++it) {                                          \
        int tl = s_tl + it * 32;                                              \
        int tg = t0 + tl - (OFF);                                             \
        v8h v = zero8;                                                        \
        if (tg >= 0) v = *(const v8h*)&hin[hbase + (size_t)tg * 64 + s_c];    \
        *(v8h*)&(DST)[tl * ST + s_c] = v;                                     \
    } } while (0)

#define MFMA_TAP(SRC, TAP) do {                                               \
    _Pragma("unroll")                                                         \
    for (int kc = 0; kc < 4; ++kc) {                                          \
        const int kof = kc * 16 + hl * 8;                                     \
        v8h aF = *(const v8h*)&wfg[(ch + ln31) * 192 + (TAP) * 64 + kof];     \
        v8h aG = *(const v8h*)&wfg[(64 + ch + ln31) * 192 + (TAP) * 64 + kof];\
        v8h b0 = *(const v8h*)&(SRC)[(tb + ln31) * ST + kof];                 \
        v8h b1 = *(const v8h*)&(SRC)[(tb + 32 + ln31) * ST + kof];            \
        accF[0] = __builtin_amdgcn_mfma_f32_32x32x16_f16(aF, b0, accF[0], 0, 0, 0); \
        accF[1] = __builtin_amdgcn_mfma_f32_32x32x16_f16(aF, b1, accF[1], 0, 0, 0); \
        accG[0] = __builtin_amdgcn_mfma_f32_32x32x16_f16(aG, b0, accG[0], 0, 0, 0); \
        accG[1] = __builtin_amdgcn_mfma_f32_32x32x16_f16(aG, b1, accG[1], 0, 0, 0); \
    } } while (0)

    // biases -> accumulator init (D row m maps to c = ch + 8q + 4hl + r)
    v16f accF[2], accG[2];
    #pragma unroll
    for (int q = 0; q < 4; ++q) {
        v4f fv = *(const v4f*)&fb[ch + 8 * q + 4 * hl];
        v4f gv = *(const v4f*)&gb[ch + 8 * q + 4 * hl];
        #pragma unroll
        for (int r = 0; r < 4; ++r) {
            accF[0][q * 4 + r] = fv[r]; accF[1][q * 4 + r] = fv[r];
            accG[0][q * 4 + r] = gv[r]; accG[1][q * 4 + r] = gv[r];
        }
    }

    STAGE(P0, 2 * dil);
    __syncthreads();                        // S1: P0 ready
    STAGE(P1, dil);                         // overlap tap1 loads with tap0 mfma
    MFMA_TAP(P0, 0);
    __syncthreads();                        // S2: P1 ready, P0 reads done
    STAGE(P0, 0);                           // overlap tap2 loads with tap1 mfma
    MFMA_TAP(P1, 1);
    __syncthreads();                        // S3: P0 ready, P1 reads done
    MFMA_TAP(P0, 2);                        // P0 now holds hin[t] (off=0) - kept

    // act = tanh(f)*sigmoid(g) = (A-1)*rcp((A+1)*(1+B)), A=e^2f, B=e^-g
    // -> P1 [t][ci] scatter
    #pragma unroll
    for (int nt = 0; nt < 2; ++nt) {
        const int tl = tb + nt * 32 + ln31;
        #pragma unroll
        for (int q = 0; q < 4; ++q) {
            v4h av;
            #pragma unroll
            for (int r = 0; r < 4; ++r) {
                float f = accF[nt][q * 4 + r];
                float g = accG[nt][q * 4 + r];
                float A = __expf(2.f * f);
                float B = __expf(-g);
                float tA = A + 1.f;
                float den = fmaf(tA, B, tA);
                av[r] = (_Float16)((A - 1.f) * __builtin_amdgcn_rcpf(den));
            }
            *(v4h*)&P1[tl * ST + ch + 8 * q + 4 * hl] = av;
        }
    }
    __syncthreads();                        // S4: act complete, tap2 reads done

    // biases -> accR/accS init (reload rb/sb here: keeps peak VGPR low)
    v16f accR[2], accS[2];
    #pragma unroll
    for (int q = 0; q < 4; ++q) {
        v4f rv = *(const v4f*)&rb[ch + 8 * q + 4 * hl];
        v4f sv = *(const v4f*)&sb[ch + 8 * q + 4 * hl];
        #pragma unroll
        for (int r = 0; r < 4; ++r) {
            accR[0][q * 4 + r] = rv[r]; accR[1][q * 4 + r] = rv[r];
            accS[0][q * 4 + r] = sv[r]; accS[1][q * 4 + r] = sv[r];
        }
    }

    #pragma unroll
    for (int kc = 0; kc < 4; ++kc) {
        const int kof = kc * 16 + hl * 8;
        v8h aR = *(const v8h*)&rs[(ch + ln31) * 64 + kof];
        v8h aS = *(const v8h*)&rs[(64 + ch + ln31) * 64 + kof];
        v8h b0 = *(const v8h*)&P1[(tb + ln31) * ST + kof];
        v8h b1 = *(const v8h*)&P1[(tb + 32 + ln31) * ST + kof];
        accR[0] = __builtin_amdgcn_mfma_f32_32x32x16_f16(aR, b0, accR[0], 0, 0, 0);
        accR[1] = __builtin_amdgcn_mfma_f32_32x32x16_f16(aR, b1, accR[1], 0, 0, 0);
        accS[0] = __builtin_amdgcn_mfma_f32_32x32x16_f16(aS, b0, accS[0], 0, 0, 0);
        accS[1] = __builtin_amdgcn_mfma_f32_32x32x16_f16(aS, b1, accS[1], 0, 0, 0);
    }

    // R epilogue in-place on P0 (holds hin tile): h_new = (h + R)*0.7071
    #pragma unroll
    for (int nt = 0; nt < 2; ++nt) {
        const int tl = tb + nt * 32 + ln31;
        #pragma unroll
        for (int q = 0; q < 4; ++q) {
            _Float16* cell = &P0[tl * ST + ch + 8 * q + 4 * hl];
            v4h hv = *(const v4h*)cell;
            v4h hn;
            #pragma unroll
            for (int r = 0; r < 4; ++r)
                hn[r] = (_Float16)(((float)hv[r] + accR[nt][q * 4 + r]) * 0.7071f);
            *(v4h*)cell = hn;
        }
    }
    __syncthreads();                        // S5: P1 rs-reads done, P0 = hout tile

    // S scatter -> P1 (act dead): skip contribution (bias already in accS)
    #pragma unroll
    for (int nt = 0; nt < 2; ++nt) {
        const int tl = tb + nt * 32 + ln31;
        #pragma unroll
        for (int q = 0; q < 4; ++q) {
            v4h sn;
            #pragma unroll
            for (int r = 0; r < 4; ++r)
                sn[r] = (_Float16)accS[nt][q * 4 + r];
            *(v4h*)&P1[tl * ST + ch + 8 * q + 4 * hl] = sn;
        }
    }
    // hout coalesced store from P0 (safe after S5)
    #pragma unroll
    for (int it = 0; it < 4; ++it) {
        int tl = s_tl + it * 32;
        *(v8h*)&hout[hbase + (size_t)(t0 + tl) * 64 + s_c] = *(const v8h*)&P0[tl * ST + s_c];
    }
    __syncthreads();                        // S6: P1 skip tile complete

    // skip coalesced RMW from P1
    #pragma unroll
    for (int it = 0; it < 4; ++it) {
        int tl = s_tl + it * 32;
        const size_t base = hbase + (size_t)(t0 + tl) * 64 + s_c;
        v8h sk = *(const v8h*)&skip[base];
        v8h pv = *(const v8h*)&P1[tl * ST + s_c];
        v8h sn;
        #pragma unroll
        for (int r = 0; r < 8; ++r)
            sn[r] = (_Float16)((float)sk[r] * skip_scale + (float)pv[r]);
        *(v8h*)&skip[base] = sn;
    }
#undef STAGE
#undef MFMA_TAP
}

// ---------------------------------------------------------------------------
// k_out: out[b][t] = ow2 @ relu(ow1 @ relu(skip[b][t][:]) + ob1) + ob2
// ---------------------------------------------------------------------------
__global__ __launch_bounds__(256) void k_out(const _Float16* __restrict__ skip,
                                             const float* __restrict__ ow1,
                                             const float* __restrict__ ob1,
                                             const float* __restrict__ ow2,
                                             const float* __restrict__ ob2,
                                             float* __restrict__ out)
{
    const int t  = blockIdx.x * 256 + threadIdx.x;
    const int bb = blockIdx.y;
    const _Float16* sp = skip + ((size_t)bb * Tn + t) * 64;
    float y[64];
    #pragma unroll
    for (int i = 0; i < 8; ++i) {
        v8h v = *(const v8h*)&sp[i * 8];
        #pragma unroll
        for (int j = 0; j < 8; ++j) y[i * 8 + j] = fmaxf((float)v[j], 0.f);
    }
    float o = ob2[0];
    for (int co = 0; co < 64; ++co) {          // weights uniform -> s_loads
        float a0 = ob1[co], a1 = 0.f;
        #pragma unroll
        for (int ci = 0; ci < 64; ci += 2) {
            a0 = fmaf(ow1[co * 64 + ci],     y[ci],     a0);
            a1 = fmaf(ow1[co * 64 + ci + 1], y[ci + 1], a1);
        }
        o = fmaf(ow2[co], fmaxf(a0 + a1, 0.f), o);
    }
    out[(size_t)bb * Tn + t] = o;
}

// ---------------------------------------------------------------------------
extern "C" void kernel_launch(void* const* d_in, const int* in_sizes, int n_in,
                              void* d_out, int out_size, void* d_ws, size_t ws_size,
                              hipStream_t stream)
{
    const float* x    = (const float*)d_in[0];
    const float* w_in = (const float*)d_in[1];
    const float* b_in = (const float*)d_in[2];
    const float* fw   = (const float*)d_in[3];
    const float* fb   = (const float*)d_in[4];
    const float* gw   = (const float*)d_in[5];
    const float* gb   = (const float*)d_in[6];
    const float* rw   = (const float*)d_in[7];
    const float* rb   = (const float*)d_in[8];
    const float* sw   = (const float*)d_in[9];
    const float* sb   = (const float*)d_in[10];
    const float* ow1  = (const float*)d_in[11];
    const float* ob1  = (const float*)d_in[12];
    const float* ow2  = (const float*)d_in[13];
    const float* ob2  = (const float*)d_in[14];
    float* out = (float*)d_out;

    const size_t n = (size_t)Bn * Tn * 64;
    _Float16* hA    = (_Float16*)d_ws;
    _Float16* hB    = hA + n;
    _Float16* skip  = hB + n;
    _Float16* wfg16 = skip + n;
    _Float16* rs16  = wfg16 + (size_t)Ln * 128 * 192;

    dim3 blk(256);
    k_prep<<<dim3((Ln * 128 * 192 + Ln * 128 * 64 + 255) / 256), blk, 0, stream>>>(
        fw, gw, rw, sw, wfg16, rs16);
    k_input<<<dim3(Tn / 256, Bn), blk, 0, stream>>>(x, w_in, b_in, hA);

    const _Float16* cur = hA;
    _Float16* nxt = hB;
    for (int l = 0; l < Ln; ++l) {
        const int d = 1 << l;                  // dilations 1..512
        k_layer<<<dim3(Tn / 128, Bn), blk, 0, stream>>>(
            cur, nxt, skip,
            wfg16 + (size_t)l * 128 * 192, rs16 + (size_t)l * 128 * 64,
            fb + l * Cn, gb + l * Cn, rb + l * Cn, sb + l * Cn,
            d, (l == 0) ? 0.f : 1.f);          // scale=0 absorbs 0xAA ws poison
        const _Float16* tmp = nxt; nxt = (_Float16*)cur; cur = tmp;
    }

    k_out<<<dim3(Tn / 256, Bn), blk, 0, stream>>>(skip, ow1, ob1, ow2, ob2, out);
}